// Round 11
// baseline (1084.843 us; speedup 1.0000x reference)
//
#include <hip/hip_runtime.h>

// SingleLSTM: B=32768, T=28, INPUT=28, HIDDEN=128, LABELS=10, fp32.
// R11: target TWO resident 512-thread blocks/CU (out-of-phase barriers).
// Unified-file budget: Wh pinned to AGPR ("+a", R8-proven) 64 + acc 16
// = 80 AGPR; arch target <=48 via: 32 rows/block (creg 8, 2 staging
// slots), Wx read from LDS as pre-built B-frags (no Wx regs),
// launch_bounds(512,4) (arch cap 64 per R5 ladder). Total ~125 <= 128
// -> 4 waves/SIMD -> 2 blocks/CU. R5's scratch disaster was UNPINNED Wh
// at cap 64; the pin forces AGPR placement.
// Structure: fp16 datapath; wave owns 16 hidden cols x 4 gates; per-lane
// c/h update; one barrier/step; early global x load / late LDS write
// (R9); W/bias pre-scaled {-L2E, 2L2E, -L2E, -L2E}; c in 2*L2E units.

typedef _Float16 f16x8 __attribute__((ext_vector_type(8)));
typedef float f32x4 __attribute__((ext_vector_type(4)));

#define HSTRIDE 136    // f16 elems; 272B row = 17*16B (b128-aligned rows)
#define L2E 1.44269504f

__global__ __launch_bounds__(512, 4)
void lstm_r11(const float* __restrict__ x,      // [B][28][28]
              const float* __restrict__ W,      // [156][512]
              const float* __restrict__ b,      // [512]
              const float* __restrict__ Wfc,    // [128][10]
              const float* __restrict__ bfc,    // [10]
              float* __restrict__ out)          // [B][10]
{
    __shared__ __align__(16) _Float16 h_s[2][32 * HSTRIDE];   // 17408 B
    __shared__ __align__(16) _Float16 xs[2][2][512];          // 4096 B
    __shared__ __align__(16) _Float16 wxf[8 * 4 * 64 * 8];    // 32768 B: [wave][g][lane][8]

    const int tid  = threadIdx.x;
    const int wave = tid >> 6;
    const int lane = tid & 63;
    const int m16  = lane & 15;
    const int quad = lane >> 4;
    const int rbase = blockIdx.x * 32;
    const int hc = wave * 16 + m16;     // this lane's hidden column

    // ---- zero h buf0 and xs (k>=28 slots must stay 0 forever) ----
    for (int i = tid; i < 32 * HSTRIDE; i += 512) h_s[0][i] = (_Float16)0.0f;
    for (int i = tid; i < 2 * 2 * 512; i += 512) ((_Float16*)xs)[i] = (_Float16)0.0f;

    // ---- Wh fragments (fp16, pre-scaled), B-layout, PINNED to AGPRs ----
    // lane holds B[k=quad*8+j][col]; Wx goes to LDS as B-frags (wxf).
    f16x8 Wh[4][4];     // [ks][gate] -- 64 AGPRs via "+a" pin
    float bias[4];
    #pragma unroll
    for (int g = 0; g < 4; g++) {
        const int col = g * 128 + wave * 16 + m16;
        const float sc = (g == 1) ? 2.0f * L2E : -L2E;
        bias[g] = sc * (b[col] + (g == 2 ? 1.0f : 0.0f));   // FORGET_BIAS folded
        // Wx B-frag for this (wave, g, lane): own slot, no race
        f16x8 w8;
        #pragma unroll
        for (int j = 0; j < 8; j++) {
            int kk = quad * 8 + j;
            w8[j] = (kk < 28) ? (_Float16)(sc * W[kk * 512 + col]) : (_Float16)0.0f;
        }
        *(f16x8*)(&wxf[(((wave << 2) | g) * 64 + lane) * 8]) = w8;
        #pragma unroll
        for (int ks = 0; ks < 4; ks++) {
            f16x8 h8;
            #pragma unroll
            for (int j = 0; j < 8; j++)
                h8[j] = (_Float16)(sc * W[(28 + ks * 32 + quad * 8 + j) * 512 + col]);
            __asm__("" : "+a"(h8));   // pin to AGPR; MFMA reads AGPR directly
            Wh[ks][g] = h8;
        }
    }

    // barrier: zero-init must complete before the permuted t=0 staging (R6 race)
    __syncthreads();

    // ---- per-thread x staging slots (32 rows x 28 k = 896 elems) ----
    const int srow  = tid / 28, sk = tid % 28;
    const int smt   = srow >> 4;
    const int soff  = (sk >> 3) * 128 + (srow & 15) * 8 + (sk & 7);
    const int sidx2 = tid + 512;
    const int srow2 = sidx2 / 28, sk2 = sidx2 % 28;
    const int smt2  = srow2 >> 4;
    const int soff2 = (sk2 >> 3) * 128 + (srow2 & 15) * 8 + (sk2 & 7);
    const bool sact2 = tid < 384;
    const float* xp  = x + (size_t)(rbase + srow)  * 784 + sk;
    const float* xp2 = x + (size_t)(rbase + srow2) * 784 + sk2;

    // stage x for t=0
    xs[0][smt][soff] = (_Float16)(*xp);
    if (sact2) xs[0][smt2][soff2] = (_Float16)(*xp2);
    __syncthreads();

    float creg[8];
    #pragma unroll
    for (int i = 0; i < 8; i++) creg[i] = 0.0f;

    const int foff  = quad * 128 + m16 * 8;          // xs A-frag offset
    const int wxoff = ((wave << 2) * 64 + lane) * 8; // wxf base for g=0

    int buf = 0;
    for (int t = 0; t < 28; t++) {
        const int nb = buf ^ 1;

        // ---- EARLY: issue global loads for t+1 (wait lands at step end) ----
        float xv0 = 0.0f, xv1 = 0.0f;
        if (t < 27) {
            xv0 = xp[(t + 1) * 28];
            if (sact2) xv1 = xp2[(t + 1) * 28];
        }

        // ---- two 16-row tiles, sequential acc (keeps arch regs low) ----
        #pragma unroll
        for (int mt = 0; mt < 2; mt++) {
            f32x4 acc[4];
            #pragma unroll
            for (int g = 0; g < 4; g++)
                acc[g] = (f32x4){bias[g], bias[g], bias[g], bias[g]};

            f16x8 ax = *(const f16x8*)(&xs[buf][mt][foff]);
            #pragma unroll
            for (int g = 0; g < 4; g++) {
                f16x8 wxg = *(const f16x8*)(&wxf[wxoff + g * 64 * 8]);
                acc[g] = __builtin_amdgcn_mfma_f32_16x16x32_f16(ax, wxg, acc[g], 0, 0, 0);
            }
            #pragma unroll
            for (int ks = 0; ks < 4; ks++) {
                f16x8 ah = *(const f16x8*)(&h_s[buf][(mt * 16 + m16) * HSTRIDE + ks * 32 + quad * 8]);
                #pragma unroll
                for (int g = 0; g < 4; g++)
                    acc[g] = __builtin_amdgcn_mfma_f32_16x16x32_f16(ah, Wh[ks][g], acc[g], 0, 0, 0);
            }

            // activation (overlaps other tile's / other block's MFMA chain)
            #pragma unroll
            for (int r = 0; r < 4; r++) {
                float ei  = __builtin_amdgcn_exp2f(acc[0][r]);   // e^-i
                float e2j = __builtin_amdgcn_exp2f(acc[1][r]);   // e^2j
                float ef  = __builtin_amdgcn_exp2f(acc[2][r]);   // e^-(f+1)
                float eo  = __builtin_amdgcn_exp2f(acc[3][r]);   // e^-o
                float A   = 1.0f + ei;
                float Bv  = e2j + 1.0f;
                float C   = 1.0f + ef;
                float AB  = A * Bv;
                float rP  = __builtin_amdgcn_rcpf(AB * C);
                float num = __builtin_fmaf(e2j, 2.0f * L2E, -2.0f * L2E);
                float cn  = __builtin_fmaf(creg[mt * 4 + r], AB * rP, num * (C * rP));
                creg[mt * 4 + r] = cn;
                float e2c = __builtin_amdgcn_exp2f(cn);          // e^2c
                float rQ  = __builtin_amdgcn_rcpf((e2c + 1.0f) * (1.0f + eo));
                float hv  = (e2c - 1.0f) * rQ;
                h_s[nb][(mt * 16 + quad * 4 + r) * HSTRIDE + hc] = (_Float16)hv;
            }
        }

        // ---- LATE: stage x(t+1) to LDS (vmcnt satisfied long ago) ----
        if (t < 27) {
            xs[nb][smt][soff] = (_Float16)xv0;
            if (sact2) xs[nb][smt2][soff2] = (_Float16)xv1;
        }
        __syncthreads();
        buf = nb;
    }

    // ---- FC epilogue: logits = h @ Wfc + bfc ----
    if (tid < 320) {
        const int row = tid / 10, lab = tid % 10;
        float acc = bfc[lab];
        #pragma unroll 8
        for (int k = 0; k < 128; k++)
            acc += (float)h_s[buf][row * HSTRIDE + k] * Wfc[k * 10 + lab];
        out[(size_t)(rbase + row) * 10 + lab] = acc;
    }
}

extern "C" void kernel_launch(void* const* d_in, const int* in_sizes, int n_in,
                              void* d_out, int out_size, void* d_ws, size_t ws_size,
                              hipStream_t stream) {
    const float* x   = (const float*)d_in[0];
    const float* W   = (const float*)d_in[1];
    const float* b   = (const float*)d_in[2];
    const float* Wfc = (const float*)d_in[3];
    const float* bfc = (const float*)d_in[4];
    float* out = (float*)d_out;

    const int B = in_sizes[0] / (28 * 28);   // 32768
    const int blocks = B / 32;               // 1024
    lstm_r11<<<blocks, 512, 0, stream>>>(x, W, b, Wfc, bfc, out);
}

// Round 12
// 334.802 us; speedup vs baseline: 3.2403x; 3.2403x over previous
//
#include <hip/hip_runtime.h>

// SingleLSTM: B=32768, T=28, INPUT=28, HIDDEN=128, LABELS=10, fp32.
// R12 = R10 + acc ping-pong (intra-wave MFMA/VALU pipelining).
// R5/R11 proved 2 blocks/CU is unreachable (Wh 64 AGPR + acc + temps >
// 128-reg budget -> scratch spill disaster). So stay at 1 block/CU
// (2 waves/SIMD, ~256 regs/wave budget) and pipeline WITHIN the wave:
// tile mt+1's 20-MFMA chain is issued BEFORE tile mt's activation, into
// the other acc buffer (acc[2][4], 32 AGPRs) -> MFMA pipe executes tile
// mt+1 while VALU runs tile mt's transcendentals (m114 co-schedule,
// single wave). 64 rows/block, 512 blocks, one barrier/step; early
// global x load / late LDS write; Wx in regs, Wh in AGPRs (compiler).
// fp16 datapath; W/bias pre-scaled {-L2E, 2L2E, -L2E, -L2E}; c in 2*L2E
// units (absmax 0.0039 stable R4-R11).

typedef _Float16 f16x8 __attribute__((ext_vector_type(8)));
typedef float f32x4 __attribute__((ext_vector_type(4)));

#define HSTRIDE 136    // f16 elems; 272B row = 17*16B (b128-aligned rows)
#define L2E 1.44269504f

__global__ __launch_bounds__(512, 2)
void lstm_r12(const float* __restrict__ x,      // [B][28][28]
              const float* __restrict__ W,      // [156][512]
              const float* __restrict__ b,      // [512]
              const float* __restrict__ Wfc,    // [128][10]
              const float* __restrict__ bfc,    // [10]
              float* __restrict__ out)          // [B][10]
{
    __shared__ __align__(16) _Float16 h_s[2][64 * HSTRIDE];   // 34816 B
    __shared__ __align__(16) _Float16 xs[2][4][512];          // 8192 B

    const int tid  = threadIdx.x;
    const int wave = tid >> 6;
    const int lane = tid & 63;
    const int m16  = lane & 15;
    const int quad = lane >> 4;
    const int rbase = blockIdx.x * 64;
    const int hc = wave * 16 + m16;     // this lane's hidden column

    // ---- zero h buf0 and xs (k>=28 slots must stay 0 forever) ----
    for (int i = tid; i < 64 * HSTRIDE; i += 512) h_s[0][i] = (_Float16)0.0f;
    for (int i = tid; i < 2 * 4 * 512; i += 512) ((_Float16*)xs)[i] = (_Float16)0.0f;

    // ---- W fragments (fp16, pre-scaled), B-layout: lane holds B[k=quad*8+j][col]
    f16x8 Wx[4];        // x rows (k<28, rest 0) -- 16 arch regs
    f16x8 Wh[4][4];     // [ks][gate] -- compiler places in AGPRs
    float bias[4];
    #pragma unroll
    for (int g = 0; g < 4; g++) {
        const int col = g * 128 + wave * 16 + m16;
        const float sc = (g == 1) ? 2.0f * L2E : -L2E;
        bias[g] = sc * (b[col] + (g == 2 ? 1.0f : 0.0f));   // FORGET_BIAS folded
        f16x8 w8;
        #pragma unroll
        for (int j = 0; j < 8; j++) {
            int kk = quad * 8 + j;
            w8[j] = (kk < 28) ? (_Float16)(sc * W[kk * 512 + col]) : (_Float16)0.0f;
        }
        Wx[g] = w8;
        #pragma unroll
        for (int ks = 0; ks < 4; ks++) {
            f16x8 h8;
            #pragma unroll
            for (int j = 0; j < 8; j++)
                h8[j] = (_Float16)(sc * W[(28 + ks * 32 + quad * 8 + j) * 512 + col]);
            Wh[ks][g] = h8;
        }
    }

    // barrier: zero-init must complete before the permuted t=0 staging (R6 race)
    __syncthreads();

    // ---- per-thread x staging slots: 64 rows x 28 k = 1792 elems, 4 slots ----
    int ssmt[4], ssoff[4];
    const float* sxp[4];
    #pragma unroll
    for (int e = 0; e < 4; e++) {
        const int idx = e * 512 + tid;
        const int srow = idx / 28, sk = idx % 28;
        ssmt[e]  = srow >> 4;
        ssoff[e] = (sk >> 3) * 128 + (srow & 15) * 8 + (sk & 7);
        sxp[e]   = x + (size_t)(rbase + srow) * 784 + sk;
    }
    const bool sact3 = tid < 256;

    // stage x for t=0
    #pragma unroll
    for (int e = 0; e < 3; e++) xs[0][ssmt[e]][ssoff[e]] = (_Float16)(*sxp[e]);
    if (sact3) xs[0][ssmt[3]][ssoff[3]] = (_Float16)(*sxp[3]);
    __syncthreads();

    float creg[16];
    #pragma unroll
    for (int i = 0; i < 16; i++) creg[i] = 0.0f;

    const int foff = quad * 128 + m16 * 8;   // xs A-frag offset

    int buf = 0;
    for (int t = 0; t < 28; t++) {
        const int nb = buf ^ 1;

        // ---- EARLY: issue global loads for t+1 (no wait until step end) ----
        float xv[4] = {0.f, 0.f, 0.f, 0.f};
        if (t < 27) {
            #pragma unroll
            for (int e = 0; e < 3; e++) xv[e] = sxp[e][(t + 1) * 28];
            if (sact3) xv[3] = sxp[3][(t + 1) * 28];
        }

        // ---- acc ping-pong across four 16-row tiles ----
        f32x4 acc[2][4];

        // tile 0 MFMA chain -> acc[0]
        {
            f16x8 ax = *(const f16x8*)(&xs[buf][0][foff]);
            #pragma unroll
            for (int g = 0; g < 4; g++) {
                acc[0][g] = (f32x4){bias[g], bias[g], bias[g], bias[g]};
                acc[0][g] = __builtin_amdgcn_mfma_f32_16x16x32_f16(ax, Wx[g], acc[0][g], 0, 0, 0);
            }
            #pragma unroll
            for (int ks = 0; ks < 4; ks++) {
                f16x8 ah = *(const f16x8*)(&h_s[buf][m16 * HSTRIDE + ks * 32 + quad * 8]);
                #pragma unroll
                for (int g = 0; g < 4; g++)
                    acc[0][g] = __builtin_amdgcn_mfma_f32_16x16x32_f16(ah, Wh[ks][g], acc[0][g], 0, 0, 0);
            }
        }

        #pragma unroll
        for (int mt = 0; mt < 4; mt++) {
            const int cur = mt & 1, nxt = cur ^ 1;

            // issue tile mt+1's MFMA chain into acc[nxt] BEFORE act(mt):
            // the MFMA pipe executes it while VALU runs act(mt)'s trans ops
            if (mt < 3) {
                f16x8 axn = *(const f16x8*)(&xs[buf][mt + 1][foff]);
                #pragma unroll
                for (int g = 0; g < 4; g++) {
                    acc[nxt][g] = (f32x4){bias[g], bias[g], bias[g], bias[g]};
                    acc[nxt][g] = __builtin_amdgcn_mfma_f32_16x16x32_f16(axn, Wx[g], acc[nxt][g], 0, 0, 0);
                }
                #pragma unroll
                for (int ks = 0; ks < 4; ks++) {
                    f16x8 ahn = *(const f16x8*)(&h_s[buf][((mt + 1) * 16 + m16) * HSTRIDE + ks * 32 + quad * 8]);
                    #pragma unroll
                    for (int g = 0; g < 4; g++)
                        acc[nxt][g] = __builtin_amdgcn_mfma_f32_16x16x32_f16(ahn, Wh[ks][g], acc[nxt][g], 0, 0, 0);
                }
            }

            // activation for tile mt (reads acc[cur])
            #pragma unroll
            for (int r = 0; r < 4; r++) {
                float ei  = __builtin_amdgcn_exp2f(acc[cur][0][r]);   // e^-i
                float e2j = __builtin_amdgcn_exp2f(acc[cur][1][r]);   // e^2j
                float ef  = __builtin_amdgcn_exp2f(acc[cur][2][r]);   // e^-(f+1)
                float eo  = __builtin_amdgcn_exp2f(acc[cur][3][r]);   // e^-o
                float A   = 1.0f + ei;
                float Bv  = e2j + 1.0f;
                float C   = 1.0f + ef;
                float AB  = A * Bv;
                float rP  = __builtin_amdgcn_rcpf(AB * C);
                float num = __builtin_fmaf(e2j, 2.0f * L2E, -2.0f * L2E);
                float cn  = __builtin_fmaf(creg[mt * 4 + r], AB * rP, num * (C * rP));
                creg[mt * 4 + r] = cn;
                float e2c = __builtin_amdgcn_exp2f(cn);               // e^2c
                float rQ  = __builtin_amdgcn_rcpf((e2c + 1.0f) * (1.0f + eo));
                float hv  = (e2c - 1.0f) * rQ;
                h_s[nb][(mt * 16 + quad * 4 + r) * HSTRIDE + hc] = (_Float16)hv;
            }
        }

        // ---- LATE: stage x(t+1) to LDS (vmcnt satisfied long ago) ----
        if (t < 27) {
            #pragma unroll
            for (int e = 0; e < 3; e++) xs[nb][ssmt[e]][ssoff[e]] = (_Float16)xv[e];
            if (sact3) xs[nb][ssmt[3]][ssoff[3]] = (_Float16)xv[3];
        }
        __syncthreads();
        buf = nb;
    }

    // ---- FC epilogue: logits = h @ Wfc + bfc (640 outputs) ----
    for (int i = tid; i < 640; i += 512) {
        const int row = i / 10, lab = i % 10;
        float acc = bfc[lab];
        #pragma unroll 8
        for (int k = 0; k < 128; k++)
            acc += (float)h_s[buf][row * HSTRIDE + k] * Wfc[k * 10 + lab];
        out[(size_t)(rbase + row) * 10 + lab] = acc;
    }
}

extern "C" void kernel_launch(void* const* d_in, const int* in_sizes, int n_in,
                              void* d_out, int out_size, void* d_ws, size_t ws_size,
                              hipStream_t stream) {
    const float* x   = (const float*)d_in[0];
    const float* W   = (const float*)d_in[1];
    const float* b   = (const float*)d_in[2];
    const float* Wfc = (const float*)d_in[3];
    const float* bfc = (const float*)d_in[4];
    float* out = (float*)d_out;

    const int B = in_sizes[0] / (28 * 28);   // 32768
    const int blocks = B / 64;               // 512
    lstm_r12<<<blocks, 512, 0, stream>>>(x, W, b, Wfc, bfc, out);
}

// Round 13
// 303.935 us; speedup vs baseline: 3.5693x; 1.1016x over previous
//
#include <hip/hip_runtime.h>

// SingleLSTM: B=32768, T=28, INPUT=28, HIDDEN=128, LABELS=10, fp32.
// R13: ONE 512-thread block per CU (256 blocks), 128 rows/block as two
// interleaved 64-row groups A,B. With h/x double-buffered, ONE barrier
// per full step orders write(t+1) vs read(t+1) for BOTH groups (the
// write of A is separated from its read by all of B's region + barrier).
// -> 28 barriers/block (R12 paid 56/CU), continuous 8-tile MFMA/act
// ping-pong between barriers (trans pipe fed while MFMA pipe runs the
// next tile), W prologue once per CU. LDS 86 KB > 80 KB forces 1
// block/CU residency so the 256-block grid must spread over all CUs.
// fp16 datapath; wave owns 16 hidden cols x 4 gates; per-lane c/h
// update; early global x loads / late LDS writes; W/bias pre-scaled
// {-L2E, 2L2E, -L2E, -L2E}; c in 2*L2E units (absmax 0.0039, R4-R12).

typedef _Float16 f16x8 __attribute__((ext_vector_type(8)));
typedef float f32x4 __attribute__((ext_vector_type(4)));

#define HSTRIDE 136    // f16 elems; 272B row = 17*16B (b128-aligned rows)
#define L2E 1.44269504f

__global__ __launch_bounds__(512, 2)
void lstm_r13(const float* __restrict__ x,      // [B][28][28]
              const float* __restrict__ W,      // [156][512]
              const float* __restrict__ b,      // [512]
              const float* __restrict__ Wfc,    // [128][10]
              const float* __restrict__ bfc,    // [10]
              float* __restrict__ out)          // [B][10]
{
    __shared__ __align__(16) _Float16 h_s[2][128 * HSTRIDE];  // 69632 B
    __shared__ __align__(16) _Float16 xs[2][8 * 512];         // 16384 B
    // total 86016 B: >80 KB -> exactly one block resident per CU

    const int tid  = threadIdx.x;
    const int wave = tid >> 6;
    const int lane = tid & 63;
    const int m16  = lane & 15;
    const int quad = lane >> 4;
    const int rbase = blockIdx.x * 128;
    const int hc = wave * 16 + m16;     // this lane's hidden column

    // ---- zero h buf0 and xs (k>=28 slots must stay 0 forever) ----
    for (int i = tid; i < 128 * HSTRIDE; i += 512) h_s[0][i] = (_Float16)0.0f;
    for (int i = tid; i < 2 * 8 * 512; i += 512) ((_Float16*)xs)[i] = (_Float16)0.0f;

    // ---- W fragments (fp16, pre-scaled), B-layout: lane holds B[k=quad*8+j][col]
    f16x8 Wx[4];        // x rows (k<28, rest 0)
    f16x8 Wh[4][4];     // [ks][gate] -- compiler places in AGPRs
    float bias[4];
    #pragma unroll
    for (int g = 0; g < 4; g++) {
        const int col = g * 128 + wave * 16 + m16;
        const float sc = (g == 1) ? 2.0f * L2E : -L2E;
        bias[g] = sc * (b[col] + (g == 2 ? 1.0f : 0.0f));   // FORGET_BIAS folded
        f16x8 w8;
        #pragma unroll
        for (int j = 0; j < 8; j++) {
            int kk = quad * 8 + j;
            w8[j] = (kk < 28) ? (_Float16)(sc * W[kk * 512 + col]) : (_Float16)0.0f;
        }
        Wx[g] = w8;
        #pragma unroll
        for (int ks = 0; ks < 4; ks++) {
            f16x8 h8;
            #pragma unroll
            for (int j = 0; j < 8; j++)
                h8[j] = (_Float16)(sc * W[(28 + ks * 32 + quad * 8 + j) * 512 + col]);
            Wh[ks][g] = h8;
        }
    }

    // barrier: zero-init must complete before the permuted t=0 staging (R6 race)
    __syncthreads();

    // ---- x staging: 128 rows x 28 k = 3584 = 7 slots x 512 threads ----
    // slot e: idx = e*512+tid; LDS offset into flattened xs[buf] (chunk =
    // srow>>4, A-frag order inside chunk); global offset relative to x+t*28.
    int lsoff[7], goff[7];
    #pragma unroll
    for (int e = 0; e < 7; e++) {
        const int idx = e * 512 + tid;
        const int srow = idx / 28, sk = idx % 28;
        lsoff[e] = (srow >> 4) * 512 + (sk >> 3) * 128 + (srow & 15) * 8 + (sk & 7);
        goff[e]  = (rbase + srow) * 784 + sk;   // < 25.7M, fits int
    }

    // stage x for t=0
    #pragma unroll
    for (int e = 0; e < 7; e++) xs[0][lsoff[e]] = (_Float16)x[goff[e]];
    __syncthreads();

    float creg[32];
    #pragma unroll
    for (int i = 0; i < 32; i++) creg[i] = 0.0f;

    const int foff = quad * 128 + m16 * 8;   // A-frag offset inside a chunk

    int buf = 0;
    for (int t = 0; t < 28; t++) {
        const int nb = buf ^ 1;

        // ---- EARLY: issue global loads for t+1 (wait lands at step end) ----
        float xv[7];
        if (t < 27) {
            const float* xt = x + (t + 1) * 28;
            #pragma unroll
            for (int e = 0; e < 7; e++) xv[e] = xt[goff[e]];
        }

        // ---- 8-tile MFMA/act ping-pong (tiles 0-3 = group A, 4-7 = B) ----
        f32x4 acc[2][4];

        // prologue: tile 0 MFMA chain -> acc[0]
        {
            f16x8 ax = *(const f16x8*)(&xs[buf][foff]);
            #pragma unroll
            for (int g = 0; g < 4; g++) {
                acc[0][g] = (f32x4){bias[g], bias[g], bias[g], bias[g]};
                acc[0][g] = __builtin_amdgcn_mfma_f32_16x16x32_f16(ax, Wx[g], acc[0][g], 0, 0, 0);
            }
            #pragma unroll
            for (int ks = 0; ks < 4; ks++) {
                f16x8 ah = *(const f16x8*)(&h_s[buf][m16 * HSTRIDE + ks * 32 + quad * 8]);
                #pragma unroll
                for (int g = 0; g < 4; g++)
                    acc[0][g] = __builtin_amdgcn_mfma_f32_16x16x32_f16(ah, Wh[ks][g], acc[0][g], 0, 0, 0);
            }
        }

        #pragma unroll
        for (int mt = 0; mt < 8; mt++) {
            const int cur = mt & 1, nxt = cur ^ 1;

            // issue tile mt+1's MFMA chain before act(mt): MFMA pipe runs
            // tile mt+1 while the trans pipe chews act(mt)
            if (mt < 7) {
                f16x8 axn = *(const f16x8*)(&xs[buf][(mt + 1) * 512 + foff]);
                #pragma unroll
                for (int g = 0; g < 4; g++) {
                    acc[nxt][g] = (f32x4){bias[g], bias[g], bias[g], bias[g]};
                    acc[nxt][g] = __builtin_amdgcn_mfma_f32_16x16x32_f16(axn, Wx[g], acc[nxt][g], 0, 0, 0);
                }
                #pragma unroll
                for (int ks = 0; ks < 4; ks++) {
                    f16x8 ahn = *(const f16x8*)(&h_s[buf][((mt + 1) * 16 + m16) * HSTRIDE + ks * 32 + quad * 8]);
                    #pragma unroll
                    for (int g = 0; g < 4; g++)
                        acc[nxt][g] = __builtin_amdgcn_mfma_f32_16x16x32_f16(ahn, Wh[ks][g], acc[nxt][g], 0, 0, 0);
                }
            }

            // activation for tile mt (reads acc[cur]); per-lane c/h update
            #pragma unroll
            for (int r = 0; r < 4; r++) {
                float ei  = __builtin_amdgcn_exp2f(acc[cur][0][r]);   // e^-i
                float e2j = __builtin_amdgcn_exp2f(acc[cur][1][r]);   // e^2j
                float ef  = __builtin_amdgcn_exp2f(acc[cur][2][r]);   // e^-(f+1)
                float eo  = __builtin_amdgcn_exp2f(acc[cur][3][r]);   // e^-o
                float A   = 1.0f + ei;
                float Bv  = e2j + 1.0f;
                float C   = 1.0f + ef;
                float AB  = A * Bv;
                float rP  = __builtin_amdgcn_rcpf(AB * C);
                float num = __builtin_fmaf(e2j, 2.0f * L2E, -2.0f * L2E);
                float cn  = __builtin_fmaf(creg[mt * 4 + r], AB * rP, num * (C * rP));
                creg[mt * 4 + r] = cn;
                float e2c = __builtin_amdgcn_exp2f(cn);               // e^2c
                float rQ  = __builtin_amdgcn_rcpf((e2c + 1.0f) * (1.0f + eo));
                float hv  = (e2c - 1.0f) * rQ;
                h_s[nb][(mt * 16 + quad * 4 + r) * HSTRIDE + hc] = (_Float16)hv;
            }
        }

        // ---- LATE: stage x(t+1) to LDS (vmcnt satisfied ~6000 cyc ago) ----
        if (t < 27) {
            #pragma unroll
            for (int e = 0; e < 7; e++) xs[nb][lsoff[e]] = (_Float16)xv[e];
        }
        __syncthreads();
        buf = nb;
    }

    // ---- FC epilogue: logits = h @ Wfc + bfc (1280 outputs) ----
    for (int i = tid; i < 1280; i += 512) {
        const int row = i / 10, lab = i % 10;
        float acc = bfc[lab];
        #pragma unroll 8
        for (int k = 0; k < 128; k++)
            acc += (float)h_s[buf][row * HSTRIDE + k] * Wfc[k * 10 + lab];
        out[(size_t)(rbase + row) * 10 + lab] = acc;
    }
}

extern "C" void kernel_launch(void* const* d_in, const int* in_sizes, int n_in,
                              void* d_out, int out_size, void* d_ws, size_t ws_size,
                              hipStream_t stream) {
    const float* x   = (const float*)d_in[0];
    const float* W   = (const float*)d_in[1];
    const float* b   = (const float*)d_in[2];
    const float* Wfc = (const float*)d_in[3];
    const float* bfc = (const float*)d_in[4];
    float* out = (float*)d_out;

    const int B = in_sizes[0] / (28 * 28);   // 32768
    const int blocks = B / 128;              // 256 = one per CU
    lstm_r13<<<blocks, 512, 0, stream>>>(x, W, b, Wfc, bfc, out);
}